// Round 10
// baseline (723.228 us; speedup 1.0000x reference)
//
#include <hip/hip_runtime.h>

#define SEQ 512
#define BATCH 256
#define INDIM 256
#define MLP 128
#define M_ROWS (SEQ * BATCH)        // 131072
#define PRE_STRIDE 136              // 128 mlp-pre + 4 gate-pre + 4 pad
#define AUX_OFF ((size_t)M_ROWS * PRE_STRIDE)  // in floats

// ws layout (floats): [0, AUX_OFF) PRE; [AUX_OFF, +136) aux;
// [BT_OFF ...) FRAGMENT-ORDERED bf16 weight pairs:
//   Btf_hi: 36864 ushort (18432 f), Btf_lo: same, bias144: 144 f.
// Fragment order: element (n, k) with nt=n>>4, l15=n&15, chunk=k>>5,
// kg=(k>>3)&3, j=k&7 lives at ((chunk*9+nt)*64 + kg*16+l15)*8 + j —
// so gemm lane (kg*16+l15) reads its 16B fragment contiguously, and a
// wave's 64 lanes read one coalesced 1KB line per (chunk,nt).
#define BT_OFF (AUX_OFF + 160)

typedef __attribute__((ext_vector_type(8))) short short8v;
typedef __attribute__((ext_vector_type(4))) float f32x4;

__device__ __forceinline__ unsigned short bf16_rtne(float f) {
  unsigned u = __float_as_uint(f);
  unsigned r = u + 0x7FFFu + ((u >> 16) & 1u);
  return (unsigned short)(r >> 16);
}
__device__ __forceinline__ void cvt2(float f, unsigned short& h,
                                     unsigned short& l) {
  h = bf16_rtne(f);
  l = bf16_rtne(f - __uint_as_float((unsigned)h << 16));
}
__device__ __forceinline__ int frag_idx(int n, int k) {
  const int nt = n >> 4, l15 = n & 15;
  const int ch = k >> 5, kg = (k >> 3) & 3, j = k & 7;
  return ((ch * 9 + nt) * 64 + kg * 16 + l15) * 8 + j;
}

// ---------------------------------------------------------------------------
// Kernel 1 (R16): prep — aux/bias unchanged; weight conversion now emits the
// FRAGMENT-ORDERED table so gemm needs no LDS transpose at all.
// ---------------------------------------------------------------------------
__global__ __launch_bounds__(256) void prep_kernel(
    const float* __restrict__ W1,
    const float* __restrict__ Wf, const float* __restrict__ Wi,
    const float* __restrict__ Wg, const float* __restrict__ Wo,
    const float* __restrict__ bf, const float* __restrict__ bi,
    const float* __restrict__ bg, const float* __restrict__ bo,
    const float* __restrict__ b1, float* __restrict__ aux,
    float* __restrict__ btbase) {
  const int tid = threadIdx.x;
  const int blk = blockIdx.x;
  unsigned short* bth = (unsigned short*)btbase;
  unsigned short* btl = (unsigned short*)(btbase + 18432);
  float* b144 = btbase + 36864;

  if (blk == 0) {
    if (tid < 128) {
      float s = 0.f;
      for (int k = 0; k < 256; ++k) s += W1[(size_t)(256 + k) * 128 + tid];
      aux[tid] = s;
    } else if (tid < 132) {
      const int g = tid - 128;
      const float* w = (g == 0) ? Wf : (g == 1) ? Wi : (g == 2) ? Wg : Wo;
      float s = 0.f;
      for (int k = 0; k < 256; ++k) s += w[256 + k];
      aux[128 + g] = s;
    } else if (tid < 136) {
      const int g = tid - 132;
      const float* bp = (g == 0) ? bf : (g == 1) ? bi : (g == 2) ? bg : bo;
      aux[132 + g] = bp[0];
    }
    if (tid < 144) {
      const float bv = (tid < 128) ? b1[tid]
                     : (tid == 128) ? bf[0] : (tid == 129) ? bi[0]
                     : (tid == 130) ? bg[0] : (tid == 131) ? bo[0] : 0.f;
      b144[tid] = bv;
    }
  } else if (blk == 1) {
    // gate rows n=128..131 (coalesced source) + zero pad n=132..143
    for (int idx = tid; idx < 1024; idx += 256) {
      const int n = 128 + (idx >> 8), k = idx & 255;
      const float* wg = (n == 128) ? Wf : (n == 129) ? Wi
                       : (n == 130) ? Wg : Wo;
      unsigned short h, l;
      cvt2(wg[k], h, l);
      const int fi = frag_idx(n, k);
      bth[fi] = h;
      btl[fi] = l;
    }
    for (int idx = tid; idx < 3072; idx += 256) {
      const int n = 132 + (idx >> 8), k = idx & 255;
      const int fi = frag_idx(n, k);
      bth[fi] = 0;
      btl[fi] = 0;
    }
  } else {
    // W1 rows k = 2(blk-2), 2(blk-2)+1; coalesced row-major reads
    const int k = 2 * (blk - 2) + (tid >> 7);
    const int n = tid & 127;
    unsigned short h, l;
    cvt2(W1[(size_t)k * 128 + n], h, l);
    const int fi = frag_idx(n, k);
    bth[fi] = h;
    btl[fi] = l;
  }
}

// ---------------------------------------------------------------------------
// Kernel 2 (R16): MFMA split-precision GEMM with NO LDS AND NO BARRIERS.
// R15 insight: each wave's A-fragments cover only its OWN 16 rows (nothing
// shared across waves -> LDS staging was a pure detour with 16 barrier
// drains/block), and B is a weight -> pre-fragmented in prep. Each lane:
//   A: load its own 32B of X (2 float4), cvt2 inline -> ah/al.
//   B: 16B per (chunk,nt) at a lane-indexed address; a wave's 64 lanes form
//      one coalesced 1KB read; table is 147KB, L2-resident for all blocks.
// 27 MFMA per chunk, 8 chunks; waves fully independent -> latency hidden by
// TLP (grid 2048 x 4 waves = 8 waves/SIMD target). Fragment values and MFMA
// order identical to R15 -> bitwise-same PRE.
// Layouts (guide-verified): C/D col=lane&15,row=(lane>>4)*4+reg [m89];
// A row=l15,k=kgl*8+j; B col=l15, same k.
// ---------------------------------------------------------------------------
__global__ __attribute__((amdgpu_waves_per_eu(1, 4))) __launch_bounds__(256)
void gemm_kernel(const float* __restrict__ X,
                 const unsigned short* __restrict__ Bth,
                 const unsigned short* __restrict__ Btl,
                 const float* __restrict__ bias144,
                 float* __restrict__ PRE) {
  const int tid = threadIdx.x;
  const int lane = tid & 63, wv = tid >> 6;
  const int l15 = lane & 15, kgl = lane >> 4;
  const size_t rowbase = (size_t)blockIdx.x * 64;
  const size_t arow = rowbase + wv * 16 + l15;   // my A row (per-lane)

  f32x4 acc[9];
#pragma unroll
  for (int nt = 0; nt < 9; ++nt) acc[nt] = (f32x4){0.f, 0.f, 0.f, 0.f};

#pragma unroll
  for (int ch = 0; ch < 8; ++ch) {
    // ---- A fragment: my own 8 X floats, converted in-register ----
    const float4 xa = *(const float4*)&X[arow * 256 + ch * 32 + kgl * 8];
    const float4 xb = *(const float4*)&X[arow * 256 + ch * 32 + kgl * 8 + 4];
    unsigned short h0, h1, h2, h3, h4, h5, h6, h7;
    unsigned short l0, l1, l2, l3, l4, l5, l6, l7;
    cvt2(xa.x, h0, l0); cvt2(xa.y, h1, l1);
    cvt2(xa.z, h2, l2); cvt2(xa.w, h3, l3);
    cvt2(xb.x, h4, l4); cvt2(xb.y, h5, l5);
    cvt2(xb.z, h6, l6); cvt2(xb.w, h7, l7);
    const short8v ah = {(short)h0, (short)h1, (short)h2, (short)h3,
                        (short)h4, (short)h5, (short)h6, (short)h7};
    const short8v al = {(short)l0, (short)l1, (short)l2, (short)l3,
                        (short)l4, (short)l5, (short)l6, (short)l7};
    // ---- B fragments direct from the L2-resident fragment table ----
#pragma unroll
    for (int nt = 0; nt < 9; ++nt) {
      const int fi = ((ch * 9 + nt) * 64 + lane) * 8;
      const short8v bh = *(const short8v*)&Bth[fi];
      const short8v bl = *(const short8v*)&Btl[fi];
      acc[nt] = __builtin_amdgcn_mfma_f32_16x16x32_bf16(ah, bh, acc[nt], 0, 0, 0);
      acc[nt] = __builtin_amdgcn_mfma_f32_16x16x32_bf16(ah, bl, acc[nt], 0, 0, 0);
      acc[nt] = __builtin_amdgcn_mfma_f32_16x16x32_bf16(al, bh, acc[nt], 0, 0, 0);
    }
  }

  // ---- epilogue: bias + store (cols >= 132 masked; 132-143 = pad) ----
#pragma unroll
  for (int nt = 0; nt < 9; ++nt) {
    const int col = nt * 16 + l15;
    if (col < 132) {
      const float bb = bias144[col];
#pragma unroll
      for (int q = 0; q < 4; ++q) {
        PRE[(rowbase + wv * 16 + kgl * 4 + q) * PRE_STRIDE + col] =
            acc[nt][q] + bb;
      }
    }
  }
}

// ---------------------------------------------------------------------------
// Kernel 3: serial recurrence — R13 version VERBATIM (proven 436.9 µs).
// ---------------------------------------------------------------------------
__device__ __forceinline__ float sigmoid_f(float x) {
  return __fdividef(1.0f, 1.0f + __expf(-x));
}
__device__ __forceinline__ float tanh_f(float x) {
  const float e = __expf(-2.0f * x);
  return __fdividef(1.0f - e, 1.0f + e);
}
__device__ __forceinline__ float readlane_f(float v, int lane) {
  return __int_as_float(__builtin_amdgcn_readlane(__float_as_int(v), lane));
}

__global__ __attribute__((amdgpu_waves_per_eu(1, 1))) __launch_bounds__(64)
void rec_kernel(
    const float* __restrict__ PRE, const float* __restrict__ W2,
    const float* __restrict__ b2, const float* __restrict__ aux,
    float* __restrict__ out) {
  __shared__ __align__(16) float h1s[128];

  const int l = threadIdx.x;
  const int b = blockIdx.x;
  const int m = l & 31, half = l >> 5;
  const int g = m >> 3;
  const int g8 = g * 8;

  float w2r[64];
#pragma unroll
  for (int u = 0; u < 64; ++u) w2r[u] = W2[(size_t)(half * 64 + u) * 32 + m];
  const float b2m = b2[m];
  const float2 s1 = *(const float2*)&aux[2 * l];
  const float4 sg = *(const float4*)&aux[128];

  float h = 0.f, c = 0.f;

  const float* pr0 = PRE + (size_t)b * PRE_STRIDE;
  const size_t ts = (size_t)BATCH * PRE_STRIDE;

  float2 p0 = *(const float2*)(pr0 + 0 * ts + 2 * l);
  float4 g0 = *(const float4*)(pr0 + 0 * ts + 128);
  float2 p1 = *(const float2*)(pr0 + 1 * ts + 2 * l);
  float4 g1 = *(const float4*)(pr0 + 1 * ts + 128);

  const float4* h1p = (const float4*)&h1s[half * 64];

  for (int t = 0; t < SEQ; ++t) {
    const float h10 = fmaxf(fmaf(h, s1.x, p0.x), 0.f);
    const float h11 = fmaxf(fmaf(h, s1.y, p0.y), 0.f);

    ((float2*)h1s)[l] = make_float2(h10, h11);
    asm volatile("" ::: "memory");

    const float zf = fmaf(h, sg.x, g0.x);
    const float zi = fmaf(h, sg.y, g0.y);
    const float zg = fmaf(h, sg.z, g0.z);
    const float zo = fmaf(h, sg.w, g0.w);
    const float cf = sigmoid_f(zf);
    const float ci = sigmoid_f(zi);
    const float cg = tanh_f(zg);
    const float co = sigmoid_f(zo);
    p0 = p1; g0 = g1;
    const int tn = (t + 2 < SEQ) ? (t + 2) : (SEQ - 1);
    p1 = *(const float2*)(pr0 + (size_t)tn * ts + 2 * l);
    g1 = *(const float4*)(pr0 + (size_t)tn * ts + 128);

    float q0 = 0.f, q1 = 0.f, q2 = 0.f, q3 = 0.f;
#pragma unroll
    for (int jj = 0; jj < 16; ++jj) {
      const float4 hv = h1p[jj];
      q0 = fmaf(hv.x, w2r[4 * jj + 0], q0);
      q1 = fmaf(hv.y, w2r[4 * jj + 1], q1);
      q2 = fmaf(hv.z, w2r[4 * jj + 2], q2);
      q3 = fmaf(hv.w, w2r[4 * jj + 3], q3);
    }
    const float part = (q0 + q1) + (q2 + q3);

    const float full = part + __shfl_xor(part, 32, 64);
    const float cm = __cosf(full + b2m);
    const int sb = (l & 32) + g8;
    const float e0 = __shfl(cm, sb + 0, 64);
    const float e1 = __shfl(cm, sb + 1, 64);
    const float e2 = __shfl(cm, sb + 2, 64);
    const float e3 = __shfl(cm, sb + 3, 64);
    const float e4 = __shfl(cm, sb + 4, 64);
    const float e5 = __shfl(cm, sb + 5, 64);
    const float e6 = __shfl(cm, sb + 6, 64);
    const float e7 = __shfl(cm, sb + 7, 64);
    float p = e0, s = e0;
    p *= e1; s += p;
    p *= e2; s += p;
    p *= e3; s += p;
    p *= e4; s += p;
    p *= e5; s += p;
    p *= e6; s += p;
    p *= e7; s += p;
    const float qv = s * 0.125f;

    const float qarg = (g == 2) ? (2.0f * qv) : qv;
    const float qs = sigmoid_f(qarg);
    const float av = (g == 2) ? (2.0f * qs - 1.0f) : qs;

    const float aF = readlane_f(av, 0);
    const float aI = readlane_f(av, 8);
    const float aG = readlane_f(av, 16);
    const float aO = readlane_f(av, 24);

    const float f  = 0.5f * (cf + aF);
    const float ii = 0.5f * (ci + aI);
    const float gg = 0.5f * (cg + aG);
    const float oo = 0.5f * (co + aO);

    c = fmaf(f, c, ii * gg);
    h = oo * tanh_f(c);

    float4 hv4o; hv4o.x = h; hv4o.y = h; hv4o.z = h; hv4o.w = h;
    *(float4*)(out + ((size_t)t * BATCH + b) * 256 + 4 * l) = hv4o;
  }

  float4 hq; hq.x = h; hq.y = h; hq.z = h; hq.w = h;
  float4 cq; cq.x = c; cq.y = c; cq.z = c; cq.w = c;
  *(float4*)(out + (size_t)SEQ * BATCH * 256 + (size_t)b * 256 + 4 * l) = hq;
  *(float4*)(out + (size_t)SEQ * BATCH * 256 + (size_t)BATCH * 256 +
             (size_t)b * 256 + 4 * l) = cq;
}

// ---------------------------------------------------------------------------
extern "C" void kernel_launch(void* const* d_in, const int* in_sizes, int n_in,
                              void* d_out, int out_size, void* d_ws,
                              size_t ws_size, hipStream_t stream) {
  const float* X  = (const float*)d_in[0];
  const float* W1 = (const float*)d_in[1];
  const float* b1 = (const float*)d_in[2];
  const float* W2 = (const float*)d_in[3];
  const float* b2 = (const float*)d_in[4];
  const float* Wf = (const float*)d_in[5];
  const float* bf = (const float*)d_in[6];
  const float* Wi = (const float*)d_in[7];
  const float* bi = (const float*)d_in[8];
  const float* Wg = (const float*)d_in[9];
  const float* bg = (const float*)d_in[10];
  const float* Wo = (const float*)d_in[11];
  const float* bo = (const float*)d_in[12];

  float* ws  = (float*)d_ws;
  float* PRE = ws;
  float* aux = ws + AUX_OFF;
  float* btbase = ws + BT_OFF;
  const unsigned short* bth = (const unsigned short*)btbase;
  const unsigned short* btl = (const unsigned short*)(btbase + 18432);
  const float* b144 = btbase + 36864;
  float* out = (float*)d_out;

  prep_kernel<<<130, 256, 0, stream>>>(W1, Wf, Wi, Wg, Wo, bf, bi, bg, bo,
                                       b1, aux, btbase);
  gemm_kernel<<<M_ROWS / 64, 256, 0, stream>>>(X, bth, btl, b144, PRE);
  rec_kernel<<<BATCH, 64, 0, stream>>>(PRE, W2, b2, aux, out);
}